// Round 7
// baseline (202.032 us; speedup 1.0000x reference)
//
#include <hip/hip_runtime.h>
#include <hip/hip_bf16.h>

// Problem constants
#define NROWS 262144
#define HISTC 24
#define FOREC 20

// MFMA fragment vector types (gfx950 16x16x32 bf16: v8bf16 in, v4f32 acc)
typedef __bf16        v8bf __attribute__((ext_vector_type(8)));
typedef float         v4f  __attribute__((ext_vector_type(4)));
typedef float         v2f  __attribute__((ext_vector_type(2)));
typedef unsigned int  v4u  __attribute__((ext_vector_type(4)));
typedef unsigned int  v2u  __attribute__((ext_vector_type(2)));

// Workspace layout (bytes): [0..16) scalars a,b,g,lam ; then swizzled bf16 weights.
// Swizzle: block (ntile,ktile) of 64 lanes x 8 bf16, elem ((nt*KT+kt)*64 + lane)*8 + j
// holding W^T[feat = nt*16 + (lane&15)][k = kt*32 + (lane>>4)*8 + j]  (OOB -> 0).
// WT4 is REPLICATED to 16 nt-slots (real nt = slot&1) so the generic cross-layer
// prefetch index ((w*4+ft)*KT+kt) is valid for layer 4 too (slot&1 == ft&1).
#define WS_WT1_OFF 64
#define WT1_ELEMS 16384    /* 16 nt * 2 kt * 512 */
#define WT2_ELEMS 65536    /* 16 nt * 8 kt * 512 */
#define WT3_ELEMS 65536
#define WT4R_ELEMS 65536   /* 16 nt-slots (real nt = slot&1) * 8 kt * 512 */

// 2*log2(e): tanh(y) = 1 - 2/(exp2(y*2log2e)+1)
#define TANH_C 2.885390081777927f

__device__ __forceinline__ unsigned short f2bf(float x) {
    unsigned u = __builtin_bit_cast(unsigned, x);
    u += 0x7FFFu + ((u >> 16) & 1u);          // round-to-nearest-even
    return (unsigned short)(u >> 16);
}

// pack two fp32 -> bf16x2 with round-half-up: 2 adds + 1 v_perm (vs ~6 instr RNE).
// Validated in rounds 0-5. (R6's v_cvt_pk_bf16_f32 + VOP3P inline asm produced
// NaN — unvalidated hand asm reverted per rigor.md.)
__device__ __forceinline__ unsigned packbf2(float a, float b) {
    unsigned ua = __builtin_bit_cast(unsigned, a) + 0x8000u;
    unsigned ub = __builtin_bit_cast(unsigned, b) + 0x8000u;
    return __builtin_amdgcn_perm(ub, ua, 0x07060302u);
}

// Barrier with LDS-visibility only: does NOT drain vmcnt, so in-flight global
// (weight-prefetch) loads survive the barrier.
__device__ __forceinline__ void lds_barrier() {
    asm volatile("s_waitcnt lgkmcnt(0)\n\ts_barrier" ::: "memory");
}

// LDS activation buffers: TWO 64x256-bf16 (32768 B each) ping-pong buffers.
// Layer n reads bin, writes bout -> ONE barrier per layer (write-visibility).
// XOR swizzle: byte_addr(row, off) = row*512 + (off ^ ((row&7)<<4)); row&7==c&7
// on all hot paths, so addresses decompose into precomputed per-thread bases.
__device__ __forceinline__ int swzi(int r, int byteoff) {
    return (r << 8) + (((byteoff) ^ ((r & 7) << 4)) >> 1);   // short index
}

// ---------------- prep: scalars + weight transpose/convert/swizzle ----------------
__global__ void prep_kernel(const float* __restrict__ w1, const float* __restrict__ w2,
                            const float* __restrict__ w3, const float* __restrict__ w4,
                            const float* __restrict__ alpha, const float* __restrict__ beta,
                            const float* __restrict__ gamma, const float* __restrict__ lmix,
                            unsigned char* __restrict__ ws)
{
    if (blockIdx.x == 104) {                    // scalar block
        int t = threadIdx.x;
        float* wsf = (float*)ws;
        if (t == 0) wsf[0] = 1.0f / (1.0f + expf(-alpha[0]));
        else if (t == 1) wsf[1] = 1.0f / (1.0f + expf(-beta[0]));
        else if (t == 2) wsf[2] = fabsf(gamma[0]);
        else if (t == 3) wsf[3] = 1.0f / (1.0f + expf(-lmix[0]));
        return;
    }
    int idx = (blockIdx.x * 256 + threadIdx.x) * 8;   // elem base, 8 per thread
    const float* src;
    int KT, Kreal, Nreal, srcN, local, ntmask;
    unsigned short* dst = (unsigned short*)(ws + WS_WT1_OFF);
    if (idx < WT1_ELEMS) {
        local = idx; src = w1; KT = 2; Kreal = 44; Nreal = 256; srcN = 256; ntmask = 255;
    } else if (idx < WT1_ELEMS + WT2_ELEMS) {
        local = idx - WT1_ELEMS; dst += WT1_ELEMS;
        src = w2; KT = 8; Kreal = 256; Nreal = 256; srcN = 256; ntmask = 255;
    } else if (idx < WT1_ELEMS + WT2_ELEMS + WT3_ELEMS) {
        local = idx - (WT1_ELEMS + WT2_ELEMS); dst += WT1_ELEMS + WT2_ELEMS;
        src = w3; KT = 8; Kreal = 256; Nreal = 256; srcN = 256; ntmask = 255;
    } else {
        local = idx - (WT1_ELEMS + WT2_ELEMS + WT3_ELEMS);
        dst += WT1_ELEMS + WT2_ELEMS + WT3_ELEMS;
        src = w4; KT = 8; Kreal = 256; Nreal = 20; srcN = 20; ntmask = 1;  // replicate
    }
    int L   = (local >> 3) & 63;
    int blk = local >> 9;
    int kt = blk % KT, nt = (blk / KT) & ntmask;
    int cc = L & 15,  qq = L >> 4;
    int feat = nt * 16 + cc;
    int kbase = kt * 32 + qq * 8;
    unsigned short tmp[8];
#pragma unroll
    for (int j = 0; j < 8; ++j) {
        int k = kbase + j;
        float v = (k < Kreal && feat < Nreal) ? src[k * srcN + feat] : 0.0f;
        tmp[j] = f2bf(v);
    }
    v4u pk;
    pk[0] = tmp[0] | ((unsigned)tmp[1] << 16);
    pk[1] = tmp[2] | ((unsigned)tmp[3] << 16);
    pk[2] = tmp[4] | ((unsigned)tmp[5] << 16);
    pk[3] = tmp[6] | ((unsigned)tmp[7] << 16);
    *(v4u*)&dst[local] = pk;
}

// ---------------- fused main kernel ----------------
// 4 waves, 64 samples/block; wave w owns 4 ftiles x 4 stiles, acc[4][4]=64 regs.
// Ping-pong activation buffers: 1 barrier/layer. A (weights): 3-slot rotating
// buffer, 2-deep prefetch; cross-layer prefetch stays in flight across the
// barrier (lgkmcnt-only). B (activations): 2-slot register double-buffer.
// EPILOGUE: tanh math expressed on v2f vectors via __builtin_elementwise_fma /
// vector add so the gfx950 backend CAN legalize to v_pk_*_f32 (compiler-
// generated packing — no hand VOP3P asm after the R6 NaN). Worst case it
// emits R5's scalar code; best case ~6 fewer VALU cy per 2 elements.
// S0 = A-rotation phase on entry: L1 S0=0 (KT=2) -> L2 S0=2 -> L3 S0=1 -> L4 0.
template<int KT, int KTN, int S0>
__device__ __forceinline__ void layer_pipe(const char* bin, char* bout,
        const v4u* __restrict__ wp, const v4u* __restrict__ wpn,
        const float* __restrict__ bias, v4u A[3][4],
        const int* be, const int* bo, const int* wb, const int* fx,
        int w, int q, int lane)
{
    v4f acc[4][4];
#pragma unroll
    for (int ft = 0; ft < 4; ++ft)
#pragma unroll
        for (int st = 0; st < 4; ++st) {
            v4f z = {0.0f, 0.0f, 0.0f, 0.0f};
            acc[ft][st] = z;
        }

    v4u Bf[2][4];
#pragma unroll
    for (int st = 0; st < 4; ++st)               // kt0 B-frags
        Bf[0][st] = *(const v4u*)(bin + be[st]);

#pragma unroll
    for (int kt = 0; kt < KT; ++kt) {
        const int cs = (S0 + kt) % 3;
        const int ps = (S0 + kt + 2) % 3;
        if (kt + 2 < KT) {
#pragma unroll
            for (int ft = 0; ft < 4; ++ft)
                A[ps][ft] = wp[((w * 4 + ft) * KT + kt + 2) * 64 + lane];
        } else {
#pragma unroll
            for (int ft = 0; ft < 4; ++ft)
                A[ps][ft] = wpn[((w * 4 + ft) * KTN + (kt + 2 - KT)) * 64 + lane];
        }
        if (kt + 1 < KT) {                       // prefetch next kt's B-frags
            const int kn = kt + 1;
#pragma unroll
            for (int st = 0; st < 4; ++st)
                Bf[kn & 1][st] = *(const v4u*)(bin + ((kn & 1) ? bo[st] : be[st]) + kn * 64);
        }
        __builtin_amdgcn_s_setprio(1);
#pragma unroll
        for (int st = 0; st < 4; ++st) {
            v8bf bb = __builtin_bit_cast(v8bf, Bf[kt & 1][st]);
#pragma unroll
            for (int ft = 0; ft < 4; ++ft)
                acc[ft][st] = __builtin_amdgcn_mfma_f32_16x16x32_bf16(
                    __builtin_bit_cast(v8bf, A[cs][ft]), bb, acc[ft][st], 0, 0, 0);
        }
        __builtin_amdgcn_s_setprio(0);
    }

    // NO barrier here: reads of bin were consumed by the MFMAs above; writes
    // go to bout (different buffer), so there is no in-place hazard.

    // Epilogue: lane (q,c) holds sample c, features base+q*4..+3 per tile.
    // tanh(acc+bi) = tanh-core(acc*C + bi*C): bias folded into the scale fma.
    const v2f C2   = {TANH_C, TANH_C};
    const v2f one2 = {1.0f, 1.0f};
    const v2f m22  = {-2.0f, -2.0f};
#pragma unroll
    for (int ft = 0; ft < 4; ++ft) {
        v4f bi = *(const v4f*)&bias[w * 64 + ft * 16 + q * 4];
        v2f bi01 = {bi[0], bi[1]}, bi23 = {bi[2], bi[3]};
        v2f bic01 = bi01 * C2, bic23 = bi23 * C2;
#pragma unroll
        for (int st = 0; st < 4; ++st) {
            v4f a = acc[ft][st];
            v2f a01 = {a[0], a[1]}, a23 = {a[2], a[3]};
            v2f t01 = __builtin_elementwise_fma(a01, C2, bic01);
            v2f t23 = __builtin_elementwise_fma(a23, C2, bic23);
            v2f p01, p23;
            p01[0] = __builtin_amdgcn_exp2f(t01[0]);
            p01[1] = __builtin_amdgcn_exp2f(t01[1]);
            p23[0] = __builtin_amdgcn_exp2f(t23[0]);
            p23[1] = __builtin_amdgcn_exp2f(t23[1]);
            v2f d01 = p01 + one2;
            v2f d23 = p23 + one2;
            v2f rc01, rc23;
            rc01[0] = __builtin_amdgcn_rcpf(d01[0]);
            rc01[1] = __builtin_amdgcn_rcpf(d01[1]);
            rc23[0] = __builtin_amdgcn_rcpf(d23[0]);
            rc23[1] = __builtin_amdgcn_rcpf(d23[1]);
            v2f x01 = __builtin_elementwise_fma(rc01, m22, one2);
            v2f x23 = __builtin_elementwise_fma(rc23, m22, one2);
            v2u d; d[0] = packbf2(x01[0], x01[1]); d[1] = packbf2(x23[0], x23[1]);
            *(v2u*)(bout + wb[st] + fx[ft]) = d;
        }
    }
    lds_barrier();   // write-visibility for the next layer (vmcnt NOT drained)
}

__global__ __launch_bounds__(256, 2) void fused_kernel(
    const float* __restrict__ history,
    const float* __restrict__ eb1, const float* __restrict__ eb2,
    const float* __restrict__ cb1, const float* __restrict__ cb2,
    const unsigned char* __restrict__ ws, float* __restrict__ out)
{
    __shared__ unsigned short buf[2][64 * 256];  // 2 x 32768 B ping-pong
    __shared__ float tp[64 * 20];                // 5120 B fp32 T_physics
    char* b0 = (char*)&buf[0][0];
    char* b1 = (char*)&buf[1][0];

    const int tid  = threadIdx.x;
    const int w    = tid >> 6;                 // 4 waves
    const int lane = tid & 63;
    const int c    = lane & 15;
    const int q    = lane >> 4;
    const int row0 = blockIdx.x << 6;          // 64 samples per WG
    const float* wsf = (const float*)ws;
    const v4u* wp1 = (const v4u*)(ws + WS_WT1_OFF);
    const v4u* wp2 = wp1 + WT1_ELEMS / 8;
    const v4u* wp3 = wp2 + WT2_ELEMS / 8;
    const v4u* wp4 = wp3 + WT3_ELEMS / 8;

    // Precomputed swizzled LDS addresses (byte offsets within a buffer):
    //  read (off = kt*64+q*16):  addr = (kt odd ? bo : be)[st] + kt*64
    //  write (off = w*128+ft*32+q*8): addr = wb[st] + fx[ft]
    const int e    = (c >> 2) & 1;
    const int d64  = e << 6;
    const int qp_r = (q * 16) ^ ((c & 3) << 4);
    int be[4], bo[4], wb[4], fx[4];
#pragma unroll
    for (int st = 0; st < 4; ++st) {
        int br = (st * 16 + c) * 512 + qp_r;
        be[st] = br + d64;
        bo[st] = br - d64;
        wb[st] = (st * 16 + c) * 512 + w * 128 + ((q * 8) ^ ((c & 1) << 4));
    }
#pragma unroll
    for (int ft = 0; ft < 4; ++ft)
        fx[ft] = (ft * 32) ^ (((c >> 1) & 3) << 5);

    // Preload layer-1 kt0/kt1 frags BEFORE staging so the L2 round-trip
    // overlaps the history load + physics (S0_L1 = 0: kt0->slot0, kt1->slot1).
    v4u A[3][4];
#pragma unroll
    for (int ft = 0; ft < 4; ++ft) {
        A[0][ft] = wp1[((w * 4 + ft) * 2 + 0) * 64 + lane];
        A[1][ft] = wp1[((w * 4 + ft) * 2 + 1) * 64 + lane];
    }

    // --- staging into buf[0]: global float4 -> bf16x4 -> ds_write_b64 ---
#pragma unroll
    for (int i = 0; i < 2; ++i) {
        int e2 = tid + i * 256;
        if (e2 < 384) {
            int r  = e2 / 6, c4 = e2 - r * 6;
            v4f h4 = *(const v4f*)&history[(long)(row0 + r) * 24 + c4 * 4];
            v2u d; d[0] = packbf2(h4[0], h4[1]); d[1] = packbf2(h4[2], h4[3]);
            *(v2u*)&buf[0][swzi(r, c4 * 8)] = d;
        }
    }
    // zero-fill cols 44..63 (pad vs stale LDS): 64 rows x 5 b64-groups
#pragma unroll
    for (int i = 0; i < 2; ++i) {
        int e2 = tid + i * 256;
        if (e2 < 320) {
            int r = e2 / 5, g = e2 - r * 5;
            v2u z = {0u, 0u};
            *(v2u*)&buf[0][swzi(r, 88 + g * 8)] = z;
        }
    }
    // physics: one thread per row; last-6 history read direct from global (L2-hot)
    if (tid < 64) {
        const float* hrow = &history[(long)(row0 + tid) * 24];
        v2f h18 = *(const v2f*)&hrow[18];
        v4f h20 = *(const v4f*)&hrow[20];
        float pa = wsf[0], pb = wsf[1], pg = wsf[2];
        float d0 = h18[0], d1 = h18[1], d2 = h20[0];
        float d3 = h20[1], d4 = h20[2], d5 = h20[3];
        float T = d5;
#pragma unroll
        for (int s = 0; s < 20; ++s) {
            float t3 = T * T * T;
            float Tn = T - pa * T;
            Tn = Tn - pb * d0;
            Tn = Tn - pg * t3;
            tp[tid * 20 + s] = Tn;
            buf[0][swzi(tid, 48 + 2 * s)] = f2bf(Tn);
            d0 = d1; d1 = d2; d2 = d3; d3 = d4; d4 = d5; d5 = Tn;
            T = Tn;
        }
    }
    lds_barrier();                                           // barrier 1

    layer_pipe<2, 8, 0>(b0, b1, wp1, wp2, eb1, A, be, bo, wb, fx, w, q, lane); // b2
    layer_pipe<8, 8, 2>(b1, b0, wp2, wp3, eb2, A, be, bo, wb, fx, w, q, lane); // b3
    layer_pipe<8, 8, 1>(b0, b1, wp3, wp4, cb1, A, be, bo, wb, fx, w, q, lane); // b4

    // Layer 4: 256 -> 20, reads buf[1]. Wave w = stile w; L3's cross-layer
    // prefetch left wp4 kt0/kt1 frags in slots 0/1 (replicated wt4: slot
    // w*4+ft, real nt = ft&1). 2-deep A pipe + B register double-buffer.
    const int b04 = (w * 16 + c) * 512 + qp_r;
    v4f acc40 = {0.0f, 0.0f, 0.0f, 0.0f}, acc41 = {0.0f, 0.0f, 0.0f, 0.0f};
    v4u bcur = *(const v4u*)(b1 + b04 + d64);
#pragma unroll
    for (int kt = 0; kt < 8; ++kt) {
        const int cs = kt % 3, ps = (kt + 2) % 3;
        if (kt + 2 < 8) {
            A[ps][0] = wp4[((w * 4 + 0) * 8 + kt + 2) * 64 + lane];
            A[ps][1] = wp4[((w * 4 + 1) * 8 + kt + 2) * 64 + lane];
        }
        v4u bnext;
        if (kt + 1 < 8)
            bnext = *(const v4u*)(b1 + b04 + (((kt + 1) & 1) ? -d64 : d64) + (kt + 1) * 64);
        acc40 = __builtin_amdgcn_mfma_f32_16x16x32_bf16(
            __builtin_bit_cast(v8bf, A[cs][0]), __builtin_bit_cast(v8bf, bcur), acc40, 0, 0, 0);
        acc41 = __builtin_amdgcn_mfma_f32_16x16x32_bf16(
            __builtin_bit_cast(v8bf, A[cs][1]), __builtin_bit_cast(v8bf, bcur), acc41, 0, 0, 0);
        if (kt + 1 < 8) bcur = bnext;
    }

    const float lam = wsf[3];
    const long sample = (long)row0 + w * 16 + c;
    float* outP = out;                         // T_pred
    float* outF = out + (long)NROWS * 20;      // T_physics
    float* outS = out + (long)NROWS * 40;      // T_soft
    {   // ftile 0: features q*4..q*4+3, all valid (<20)
        int f0 = q * 4;
        v4f bi  = *(const v4f*)&cb2[f0];
        v4f tph = *(const v4f*)&tp[(w * 16 + c) * 20 + f0];
        v4f ts, pr;
#pragma unroll
        for (int r = 0; r < 4; ++r) {
            ts[r] = acc40[r] + bi[r];
            pr[r] = tph[r] + lam * ts[r];
        }
        *(v4f*)&outS[sample * 20 + f0] = ts;
        *(v4f*)&outP[sample * 20 + f0] = pr;
        *(v4f*)&outF[sample * 20 + f0] = tph;
    }
    if (q == 0) {  // ftile 1: features 16..19 valid only for q==0
        v4f bi  = *(const v4f*)&cb2[16];
        v4f tph = *(const v4f*)&tp[(w * 16 + c) * 20 + 16];
        v4f ts, pr;
#pragma unroll
        for (int r = 0; r < 4; ++r) {
            ts[r] = acc41[r] + bi[r];
            pr[r] = tph[r] + lam * ts[r];
        }
        *(v4f*)&outS[sample * 20 + 16] = ts;
        *(v4f*)&outP[sample * 20 + 16] = pr;
        *(v4f*)&outF[sample * 20 + 16] = tph;
    }
}

extern "C" void kernel_launch(void* const* d_in, const int* in_sizes, int n_in,
                              void* d_out, int out_size, void* d_ws, size_t ws_size,
                              hipStream_t stream)
{
    const float* history = (const float*)d_in[0];
    const float* enc_w1  = (const float*)d_in[1];
    const float* enc_b1  = (const float*)d_in[2];
    const float* enc_w2  = (const float*)d_in[3];
    const float* enc_b2  = (const float*)d_in[4];
    const float* cor_w1  = (const float*)d_in[5];
    const float* cor_b1  = (const float*)d_in[6];
    const float* cor_w2  = (const float*)d_in[7];
    const float* cor_b2  = (const float*)d_in[8];
    const float* alpha   = (const float*)d_in[9];
    const float* beta    = (const float*)d_in[10];
    const float* gamma   = (const float*)d_in[11];
    /* d_in[12] = tau, unused (TAU_INT compile-time) */
    const float* lmix    = (const float*)d_in[13];

    prep_kernel<<<105, 256, 0, stream>>>(enc_w1, enc_w2, cor_w1, cor_w2,
                                         alpha, beta, gamma, lmix,
                                         (unsigned char*)d_ws);
    fused_kernel<<<NROWS / 64, 256, 0, stream>>>(history, enc_b1, enc_b2, cor_b1, cor_b2,
                                                 (const unsigned char*)d_ws, (float*)d_out);
}

// Round 8
// 200.976 us; speedup vs baseline: 1.0053x; 1.0053x over previous
//
#include <hip/hip_runtime.h>
#include <hip/hip_bf16.h>

// Problem constants
#define NROWS 262144
#define HISTC 24
#define FOREC 20
#define BROWS 128          // samples per block (R8: doubled to halve L2 weight traffic)

// MFMA fragment vector types (gfx950 16x16x32 bf16: v8bf16 in, v4f32 acc)
typedef __bf16        v8bf __attribute__((ext_vector_type(8)));
typedef float         v4f  __attribute__((ext_vector_type(4)));
typedef float         v2f  __attribute__((ext_vector_type(2)));
typedef unsigned int  v4u  __attribute__((ext_vector_type(4)));
typedef unsigned int  v2u  __attribute__((ext_vector_type(2)));

// Workspace layout (bytes): [0..16) scalars a,b,g,lam ; then swizzled bf16 weights.
// Swizzle: block (ntile,ktile) of 64 lanes x 8 bf16, elem ((nt*KT+kt)*64 + lane)*8 + j
// holding W^T[feat = nt*16 + (lane&15)][k = kt*32 + (lane>>4)*8 + j]  (OOB -> 0).
// WT4 is REPLICATED to 16 nt-slots (real nt = slot&1) so the cross-layer prefetch
// index ((w*4+ft)*KT+kt) is valid for layer 4 too (slot&1 == ft&1).
#define WS_WT1_OFF 64
#define WT1_ELEMS 16384    /* 16 nt * 2 kt * 512 */
#define WT2_ELEMS 65536    /* 16 nt * 8 kt * 512 */
#define WT3_ELEMS 65536
#define WT4R_ELEMS 65536   /* 16 nt-slots (real nt = slot&1) * 8 kt * 512 */

// 2*log2(e): tanh(y) = 1 - 2/(exp2(y*2log2e)+1)
#define TANH_C 2.885390081777927f

__device__ __forceinline__ unsigned short f2bf(float x) {
    unsigned u = __builtin_bit_cast(unsigned, x);
    u += 0x7FFFu + ((u >> 16) & 1u);          // round-to-nearest-even
    return (unsigned short)(u >> 16);
}

// pack two fp32 -> bf16x2 with round-half-up: 2 adds + 1 v_perm (validated R0-R7).
__device__ __forceinline__ unsigned packbf2(float a, float b) {
    unsigned ua = __builtin_bit_cast(unsigned, a) + 0x8000u;
    unsigned ub = __builtin_bit_cast(unsigned, b) + 0x8000u;
    return __builtin_amdgcn_perm(ub, ua, 0x07060302u);
}

// Barrier with LDS-visibility only: does NOT drain vmcnt, so in-flight global
// (weight-prefetch) loads survive the barrier.
__device__ __forceinline__ void lds_barrier() {
    asm volatile("s_waitcnt lgkmcnt(0)\n\ts_barrier" ::: "memory");
}

// LDS activation buffer: 128 rows x 256 bf16 = 65536 B, in-place (2 barriers per
// layer — barrier count proven non-causal in R5). XOR swizzle:
// byte_addr(row, off) = row*512 + (off ^ ((row&7)<<4)); row&7 == c&7 on all hot
// paths (row = st*16+c), so hot addresses decompose into precomputed bases and
// the st-dimension becomes a compile-time offset (st*8192).
__device__ __forceinline__ int swzi(int r, int byteoff) {
    return (r << 8) + (((byteoff) ^ ((r & 7) << 4)) >> 1);   // short index
}

// ---------------- prep: scalars + weight transpose/convert/swizzle ----------------
__global__ void prep_kernel(const float* __restrict__ w1, const float* __restrict__ w2,
                            const float* __restrict__ w3, const float* __restrict__ w4,
                            const float* __restrict__ alpha, const float* __restrict__ beta,
                            const float* __restrict__ gamma, const float* __restrict__ lmix,
                            unsigned char* __restrict__ ws)
{
    if (blockIdx.x == 104) {                    // scalar block
        int t = threadIdx.x;
        float* wsf = (float*)ws;
        if (t == 0) wsf[0] = 1.0f / (1.0f + expf(-alpha[0]));
        else if (t == 1) wsf[1] = 1.0f / (1.0f + expf(-beta[0]));
        else if (t == 2) wsf[2] = fabsf(gamma[0]);
        else if (t == 3) wsf[3] = 1.0f / (1.0f + expf(-lmix[0]));
        return;
    }
    int idx = (blockIdx.x * 256 + threadIdx.x) * 8;   // elem base, 8 per thread
    const float* src;
    int KT, Kreal, Nreal, srcN, local, ntmask;
    unsigned short* dst = (unsigned short*)(ws + WS_WT1_OFF);
    if (idx < WT1_ELEMS) {
        local = idx; src = w1; KT = 2; Kreal = 44; Nreal = 256; srcN = 256; ntmask = 255;
    } else if (idx < WT1_ELEMS + WT2_ELEMS) {
        local = idx - WT1_ELEMS; dst += WT1_ELEMS;
        src = w2; KT = 8; Kreal = 256; Nreal = 256; srcN = 256; ntmask = 255;
    } else if (idx < WT1_ELEMS + WT2_ELEMS + WT3_ELEMS) {
        local = idx - (WT1_ELEMS + WT2_ELEMS); dst += WT1_ELEMS + WT2_ELEMS;
        src = w3; KT = 8; Kreal = 256; Nreal = 256; srcN = 256; ntmask = 255;
    } else {
        local = idx - (WT1_ELEMS + WT2_ELEMS + WT3_ELEMS);
        dst += WT1_ELEMS + WT2_ELEMS + WT3_ELEMS;
        src = w4; KT = 8; Kreal = 256; Nreal = 20; srcN = 20; ntmask = 1;  // replicate
    }
    int L   = (local >> 3) & 63;
    int blk = local >> 9;
    int kt = blk % KT, nt = (blk / KT) & ntmask;
    int cc = L & 15,  qq = L >> 4;
    int feat = nt * 16 + cc;
    int kbase = kt * 32 + qq * 8;
    unsigned short tmp[8];
#pragma unroll
    for (int j = 0; j < 8; ++j) {
        int k = kbase + j;
        float v = (k < Kreal && feat < Nreal) ? src[k * srcN + feat] : 0.0f;
        tmp[j] = f2bf(v);
    }
    v4u pk;
    pk[0] = tmp[0] | ((unsigned)tmp[1] << 16);
    pk[1] = tmp[2] | ((unsigned)tmp[3] << 16);
    pk[2] = tmp[4] | ((unsigned)tmp[5] << 16);
    pk[3] = tmp[6] | ((unsigned)tmp[7] << 16);
    *(v4u*)&dst[local] = pk;
}

// ---------------- fused main kernel ----------------
// R8 theory: all prior variants re-fetched the full ~426 KB weight set from L2
// per 64-sample block (1.75 GB total ~= 50 us of L2 time) — the only term never
// varied across R0-R7 while time sat at 122-128 us. This round each block does
// 128 samples: wave w owns 4 ftiles x 8 stiles (acc[4][8] = 128 VGPRs), so the
// same weight frags are amortized over 2x samples -> weight traffic halves.
// B-frags processed in two half-bursts (st 0-3 / 4-7) through a 32-reg Bf[2][4]
// rotating buffer: each half-burst's ds_reads hide under the other half's 16
// MFMAs. A (weights): 2-slot alternating, 1-deep prefetch; last kt prefetches
// next layer's kt0, staying in flight across tanh + barriers (lgkmcnt-only).
template<int KT, int KTN>
__device__ __forceinline__ void layer_pipe(char* bufc,
        const v4u* __restrict__ wp, const v4u* __restrict__ wpn,
        const float* __restrict__ bias, v4u A[2][4],
        int be0, int bo0, const int* wfx,
        int w, int q, int lane)
{
    v4f acc[4][8];
#pragma unroll
    for (int ft = 0; ft < 4; ++ft)
#pragma unroll
        for (int st = 0; st < 8; ++st) {
            v4f z = {0.0f, 0.0f, 0.0f, 0.0f};
            acc[ft][st] = z;
        }

    v4u Bf[2][4];
#pragma unroll
    for (int j = 0; j < 4; ++j)                  // kt0, st-group 0 (st=0..3)
        Bf[0][j] = *(const v4u*)(bufc + be0 + j * 8192);

#pragma unroll
    for (int kt = 0; kt < KT; ++kt) {
        const int cs = kt & 1;
        const int ps = cs ^ 1;
        // A: 1-deep prefetch (next kt, or next layer's kt0 at the tail)
        if (kt + 1 < KT) {
#pragma unroll
            for (int ft = 0; ft < 4; ++ft)
                A[ps][ft] = wp[((w * 4 + ft) * KT + kt + 1) * 64 + lane];
        } else {
#pragma unroll
            for (int ft = 0; ft < 4; ++ft)
                A[ps][ft] = wpn[((w * 4 + ft) * KTN + 0) * 64 + lane];
        }
        // B: st-group 1 (st=4..7) of current kt
        {
            const int rb = cs ? bo0 : be0;
#pragma unroll
            for (int j = 0; j < 4; ++j)
                Bf[1][j] = *(const v4u*)(bufc + rb + (4 + j) * 8192 + kt * 64);
        }
        __builtin_amdgcn_s_setprio(1);
#pragma unroll
        for (int j = 0; j < 4; ++j) {            // MFMA burst: st-group 0
            v8bf bb = __builtin_bit_cast(v8bf, Bf[0][j]);
#pragma unroll
            for (int ft = 0; ft < 4; ++ft)
                acc[ft][j] = __builtin_amdgcn_mfma_f32_16x16x32_bf16(
                    __builtin_bit_cast(v8bf, A[cs][ft]), bb, acc[ft][j], 0, 0, 0);
        }
        __builtin_amdgcn_s_setprio(0);
        // B: st-group 0 of NEXT kt (overwrites consumed Bf[0])
        if (kt + 1 < KT) {
            const int rb = ps ? bo0 : be0;       // (kt+1)&1 == ps
#pragma unroll
            for (int j = 0; j < 4; ++j)
                Bf[0][j] = *(const v4u*)(bufc + rb + j * 8192 + (kt + 1) * 64);
        }
        __builtin_amdgcn_s_setprio(1);
#pragma unroll
        for (int j = 0; j < 4; ++j) {            // MFMA burst: st-group 1
            v8bf bb = __builtin_bit_cast(v8bf, Bf[1][j]);
#pragma unroll
            for (int ft = 0; ft < 4; ++ft)
                acc[ft][4 + j] = __builtin_amdgcn_mfma_f32_16x16x32_bf16(
                    __builtin_bit_cast(v8bf, A[cs][ft]), bb, acc[ft][4 + j], 0, 0, 0);
        }
        __builtin_amdgcn_s_setprio(0);
    }

    lds_barrier();   // all reads done before in-place overwrite (vmcnt NOT drained)

    // Epilogue: lane (q,c) holds sample c of each stile, features base+q*4..+3.
    // tanh(acc+bi) = tanh-core(acc*C + bi*C); v2f math so backend packs (R7).
    const v2f C2   = {TANH_C, TANH_C};
    const v2f one2 = {1.0f, 1.0f};
    const v2f m22  = {-2.0f, -2.0f};
#pragma unroll
    for (int ft = 0; ft < 4; ++ft) {
        v4f bi = *(const v4f*)&bias[w * 64 + ft * 16 + q * 4];
        v2f bi01 = {bi[0], bi[1]}, bi23 = {bi[2], bi[3]};
        v2f bic01 = bi01 * C2, bic23 = bi23 * C2;
#pragma unroll
        for (int st = 0; st < 8; ++st) {
            v4f a = acc[ft][st];
            v2f a01 = {a[0], a[1]}, a23 = {a[2], a[3]};
            v2f t01 = __builtin_elementwise_fma(a01, C2, bic01);
            v2f t23 = __builtin_elementwise_fma(a23, C2, bic23);
            v2f p01, p23;
            p01[0] = __builtin_amdgcn_exp2f(t01[0]);
            p01[1] = __builtin_amdgcn_exp2f(t01[1]);
            p23[0] = __builtin_amdgcn_exp2f(t23[0]);
            p23[1] = __builtin_amdgcn_exp2f(t23[1]);
            v2f d01 = p01 + one2;
            v2f d23 = p23 + one2;
            v2f rc01, rc23;
            rc01[0] = __builtin_amdgcn_rcpf(d01[0]);
            rc01[1] = __builtin_amdgcn_rcpf(d01[1]);
            rc23[0] = __builtin_amdgcn_rcpf(d23[0]);
            rc23[1] = __builtin_amdgcn_rcpf(d23[1]);
            v2f x01 = __builtin_elementwise_fma(rc01, m22, one2);
            v2f x23 = __builtin_elementwise_fma(rc23, m22, one2);
            v2u d; d[0] = packbf2(x01[0], x01[1]); d[1] = packbf2(x23[0], x23[1]);
            *(v2u*)(bufc + wfx[ft] + st * 8192) = d;
        }
    }
    lds_barrier();   // write-visibility for the next layer (vmcnt NOT drained)
}

__global__ __launch_bounds__(256, 2) void fused_kernel(
    const float* __restrict__ history,
    const float* __restrict__ eb1, const float* __restrict__ eb2,
    const float* __restrict__ cb1, const float* __restrict__ cb2,
    const unsigned char* __restrict__ ws, float* __restrict__ out)
{
    __shared__ unsigned short buf[BROWS * 256];  // 65536 B, in-place act buffer
    __shared__ float tp[BROWS * 20];             // 10240 B fp32 T_physics
    char* bufc = (char*)buf;
    // total LDS 75776 B <= 81920 = 160K/2 -> 2 blocks/CU

    const int tid  = threadIdx.x;
    const int w    = tid >> 6;                 // 4 waves
    const int lane = tid & 63;
    const int c    = lane & 15;
    const int q    = lane >> 4;
    const int row0 = blockIdx.x << 7;          // 128 samples per WG
    const float* wsf = (const float*)ws;
    const v4u* wp1 = (const v4u*)(ws + WS_WT1_OFF);
    const v4u* wp2 = wp1 + WT1_ELEMS / 8;
    const v4u* wp3 = wp2 + WT2_ELEMS / 8;
    const v4u* wp4 = wp3 + WT3_ELEMS / 8;

    // Precomputed swizzled LDS bases (byte offsets; st-dim is a compile-time
    // st*8192 immediate on every hot access):
    //  read  (row=st*16+c, off=kt*64+q*16): addr = (kt odd ? bo0 : be0) + st*8192 + kt*64
    //  write (off = w*128+ft*32+q*8):       addr = wfx[ft] + st*8192
    const int e    = (c >> 2) & 1;
    const int d64  = e << 6;
    const int qp_r = (q * 16) ^ ((c & 3) << 4);
    const int be0  = c * 512 + qp_r + d64;
    const int bo0  = c * 512 + qp_r - d64;
    int wfx[4];
#pragma unroll
    for (int ft = 0; ft < 4; ++ft)
        wfx[ft] = c * 512 + w * 128 + ((ft * 32 + q * 8) ^ ((c & 7) << 4));

    // Preload layer-1 kt0 frags BEFORE staging so the L2 round-trip overlaps
    // the history load + physics (2-slot A: entry slot is always 0, KT even).
    v4u A[2][4];
#pragma unroll
    for (int ft = 0; ft < 4; ++ft)
        A[0][ft] = wp1[((w * 4 + ft) * 2 + 0) * 64 + lane];

    // --- staging into buf: global float4 -> bf16x4 -> ds_write_b64 ---
    // 128 rows x 6 float4-groups = 768 tasks = exactly 3 per thread.
#pragma unroll
    for (int i = 0; i < 3; ++i) {
        int e2 = tid + i * 256;
        int r  = e2 / 6, c4 = e2 - r * 6;
        v4f h4 = *(const v4f*)&history[(long)(row0 + r) * 24 + c4 * 4];
        v2u d; d[0] = packbf2(h4[0], h4[1]); d[1] = packbf2(h4[2], h4[3]);
        *(v2u*)&buf[swzi(r, c4 * 8)] = d;
    }
    // zero-fill cols 44..63 (pad vs stale LDS): 128 rows x 5 b64-groups = 640
#pragma unroll
    for (int i = 0; i < 3; ++i) {
        int e2 = tid + i * 256;
        if (e2 < 640) {
            int r = e2 / 5, g = e2 - r * 5;
            v2u z = {0u, 0u};
            *(v2u*)&buf[swzi(r, 88 + g * 8)] = z;
        }
    }
    // physics: one thread per row; last-6 history read direct from global (L2-hot)
    if (tid < BROWS) {
        const float* hrow = &history[(long)(row0 + tid) * 24];
        v2f h18 = *(const v2f*)&hrow[18];
        v4f h20 = *(const v4f*)&hrow[20];
        float pa = wsf[0], pb = wsf[1], pg = wsf[2];
        float d0 = h18[0], d1 = h18[1], d2 = h20[0];
        float d3 = h20[1], d4 = h20[2], d5 = h20[3];
        float T = d5;
#pragma unroll
        for (int s = 0; s < 20; ++s) {
            float t3 = T * T * T;
            float Tn = T - pa * T;
            Tn = Tn - pb * d0;
            Tn = Tn - pg * t3;
            tp[tid * 20 + s] = Tn;
            buf[swzi(tid, 48 + 2 * s)] = f2bf(Tn);
            d0 = d1; d1 = d2; d2 = d3; d3 = d4; d4 = d5; d5 = Tn;
            T = Tn;
        }
    }
    lds_barrier();

    layer_pipe<2, 8>(bufc, wp1, wp2, eb1, A, be0, bo0, wfx, w, q, lane);
    layer_pipe<8, 8>(bufc, wp2, wp3, eb2, A, be0, bo0, wfx, w, q, lane);
    layer_pipe<8, 8>(bufc, wp3, wp4, cb1, A, be0, bo0, wfx, w, q, lane);

    // Layer 4: 256 -> 20. Wave w handles stiles w*2, w*2+1 (2 x 16 samples),
    // both real ftiles (replicated wt4: slots w*4+0/1, real nt = slot&1 = ft).
    // L3's tail prefetch left wt4 kt0 in A[0][0..1]. 2-slot A + 2-slot B pipe.
    const int b4e = be0 + w * 16384;     // row = (w*2+s2)*16 + c; s2 via +8192 imm
    const int b4o = bo0 + w * 16384;
    v4f a4[2][2];                        // [s2][ft]
#pragma unroll
    for (int s2 = 0; s2 < 2; ++s2)
#pragma unroll
        for (int ft = 0; ft < 2; ++ft) {
            v4f z = {0.0f, 0.0f, 0.0f, 0.0f};
            a4[s2][ft] = z;
        }
    v4u Aw[2][2];
    Aw[0][0] = A[0][0]; Aw[0][1] = A[0][1];
    v4u B4[2][2];
    B4[0][0] = *(const v4u*)(bufc + b4e);
    B4[0][1] = *(const v4u*)(bufc + b4e + 8192);
#pragma unroll
    for (int kt = 0; kt < 8; ++kt) {
        const int cs = kt & 1, ps = cs ^ 1;
        if (kt + 1 < 8) {
            Aw[ps][0] = wp4[((w * 4 + 0) * 8 + kt + 1) * 64 + lane];
            Aw[ps][1] = wp4[((w * 4 + 1) * 8 + kt + 1) * 64 + lane];
            const int rb = ps ? b4o : b4e;
            B4[ps][0] = *(const v4u*)(bufc + rb + (kt + 1) * 64);
            B4[ps][1] = *(const v4u*)(bufc + rb + 8192 + (kt + 1) * 64);
        }
#pragma unroll
        for (int s2 = 0; s2 < 2; ++s2) {
            v8bf bb = __builtin_bit_cast(v8bf, B4[cs][s2]);
#pragma unroll
            for (int ft = 0; ft < 2; ++ft)
                a4[s2][ft] = __builtin_amdgcn_mfma_f32_16x16x32_bf16(
                    __builtin_bit_cast(v8bf, Aw[cs][ft]), bb, a4[s2][ft], 0, 0, 0);
        }
    }

    const float lam = wsf[3];
    float* outP = out;                         // T_pred
    float* outF = out + (long)NROWS * 20;      // T_physics
    float* outS = out + (long)NROWS * 40;      // T_soft
#pragma unroll
    for (int s2 = 0; s2 < 2; ++s2) {
        const int trow = (w * 2 + s2) * 16 + c;
        const long sample = (long)row0 + trow;
        {   // ftile 0: features q*4..q*4+3, all valid (<16)
            int f0 = q * 4;
            v4f bi  = *(const v4f*)&cb2[f0];
            v4f tph = *(const v4f*)&tp[trow * 20 + f0];
            v4f ts, pr;
#pragma unroll
            for (int r = 0; r < 4; ++r) {
                ts[r] = a4[s2][0][r] + bi[r];
                pr[r] = tph[r] + lam * ts[r];
            }
            *(v4f*)&outS[sample * 20 + f0] = ts;
            *(v4f*)&outP[sample * 20 + f0] = pr;
            *(v4f*)&outF[sample * 20 + f0] = tph;
        }
        if (q == 0) {  // ftile 1: features 16..19 valid only for q==0
            v4f bi  = *(const v4f*)&cb2[16];
            v4f tph = *(const v4f*)&tp[trow * 20 + 16];
            v4f ts, pr;
#pragma unroll
            for (int r = 0; r < 4; ++r) {
                ts[r] = a4[s2][1][r] + bi[r];
                pr[r] = tph[r] + lam * ts[r];
            }
            *(v4f*)&outS[sample * 20 + 16] = ts;
            *(v4f*)&outP[sample * 20 + 16] = pr;
            *(v4f*)&outF[sample * 20 + 16] = tph;
        }
    }
}

extern "C" void kernel_launch(void* const* d_in, const int* in_sizes, int n_in,
                              void* d_out, int out_size, void* d_ws, size_t ws_size,
                              hipStream_t stream)
{
    const float* history = (const float*)d_in[0];
    const float* enc_w1  = (const float*)d_in[1];
    const float* enc_b1  = (const float*)d_in[2];
    const float* enc_w2  = (const float*)d_in[3];
    const float* enc_b2  = (const float*)d_in[4];
    const float* cor_w1  = (const float*)d_in[5];
    const float* cor_b1  = (const float*)d_in[6];
    const float* cor_w2  = (const float*)d_in[7];
    const float* cor_b2  = (const float*)d_in[8];
    const float* alpha   = (const float*)d_in[9];
    const float* beta    = (const float*)d_in[10];
    const float* gamma   = (const float*)d_in[11];
    /* d_in[12] = tau, unused (TAU_INT compile-time) */
    const float* lmix    = (const float*)d_in[13];

    prep_kernel<<<105, 256, 0, stream>>>(enc_w1, enc_w2, cor_w1, cor_w2,
                                         alpha, beta, gamma, lmix,
                                         (unsigned char*)d_ws);
    fused_kernel<<<NROWS / BROWS, 256, 0, stream>>>(history, enc_b1, enc_b2,
                                                    cor_b1, cor_b2,
                                                    (const unsigned char*)d_ws,
                                                    (float*)d_out);
}